// Round 7
// baseline (271.150 us; speedup 1.0000x reference)
//
#include <hip/hip_runtime.h>
#include <hip/hip_bf16.h>
#include <math.h>

// MultiHash R13: encode DIRECTLY in MFMA A-fragment layout; delete the feat
// LDS staging (sF) and its transpose round-trip entirely.
// A-frag layout (m120-verified): lane(ln,q) holds A[row=ln][k=q*8+j]; with
// F=2, frag elem j = feature (j&1) of level q*4+(j>>1). So lane(ln,q)
// encodes levels q*4..q*4+3 of sample mt*16+ln — same 1024 (sample,level)
// tasks per block, same 64 gathers/lane, same per-task math (bitwise-
// identical output); only the lane->task mapping changes.
//   - LDS = sA only = 9216 B -> 17 blocks/CU by LDS.
//   - per-half frag regs transient (16 VGPR); est. live ~100-115 -> natural
//     <=128 -> 4 waves/SIMD tier = 16 blocks/CU (50%) with NO cap
//     (R8 lesson: launch_bounds caps throttle gather ILP; (64,4) spilled 3x
//     at live~145 — here the live set is far smaller).
//   - res.r[q*4+t] would be runtime-indexed kernarg (rule #20 scratch):
//     replaced by 2 cndmask selects per t on q, hoisted before the halves.
// Session ledger: R6 187 (8 blk/CU) | R8 226 ((64,3) cap) | R10 232 (pair
// trick, flat) | R11 346 (spill) | R12 204 (LDS-only occupancy, 11 blk/CU).
// Kept: weight-split prepass into d_ws, split-bf16 MFMA, sA transpose for
// layers 2/3, epilogues (R6-validated; absmax 1.49e-8 vs 8.9e-8).

#define TBL_MASK 16383u
#define PRIME1   2654435761u

typedef __attribute__((ext_vector_type(8))) short short8;
typedef __attribute__((ext_vector_type(4))) float f32x4;
typedef __attribute__((ext_vector_type(4))) unsigned int uint4v;

struct ResArr { float r[16]; };

__device__ __forceinline__ unsigned short bf16rn(float f) {
    __hip_bfloat16 h = __float2bfloat16(f);   // RNE
    return __builtin_bit_cast(unsigned short, h);
}
__device__ __forceinline__ float bf16tof(unsigned short u) {
    unsigned int xx = ((unsigned int)u) << 16;
    return __builtin_bit_cast(float, xx);
}
__device__ __forceinline__ short8 ld8(const unsigned short* p) {
    return __builtin_bit_cast(short8, *(const uint4v*)p);
}

#define MFMA(a, b, c) __builtin_amdgcn_mfma_f32_16x16x32_bf16((a), (b), (c), 0, 0, 0)

// ---- workspace layout (ushort offsets), 16B-aligned blocks ----
#define W1H_OFF 0        // [64][32]
#define W1L_OFF 2048
#define W2H_OFF 4096     // [64][64]
#define W2L_OFF 8192
#define W3H_OFF 12288    // [16][64], rows 3..15 zero
#define W3L_OFF 13312
#define WS_USHORTS 14336 // 28672 B

__global__ __launch_bounds__(256) void split_weights(
    const float* __restrict__ W1, const float* __restrict__ W2,
    const float* __restrict__ W3, unsigned short* __restrict__ ws)
{
    const int t = blockIdx.x * blockDim.x + threadIdx.x;
    const int stride = gridDim.x * blockDim.x;
    for (int i = t; i < 2048; i += stride) {
        const float v = W1[i];
        const unsigned short hb = bf16rn(v);
        ws[W1H_OFF + i] = hb;
        ws[W1L_OFF + i] = bf16rn(v - bf16tof(hb));
    }
    for (int i = t; i < 4096; i += stride) {
        const float v = W2[i];
        const unsigned short hb = bf16rn(v);
        ws[W2H_OFF + i] = hb;
        ws[W2L_OFF + i] = bf16rn(v - bf16tof(hb));
    }
    for (int i = t; i < 1024; i += stride) {
        const float v = (i < 192) ? W3[i] : 0.0f;   // W3 is [3][64]; pad to 16 rows
        const unsigned short hb = bf16rn(v);
        ws[W3H_OFF + i] = hb;
        ws[W3L_OFF + i] = bf16rn(v - bf16tof(hb));
    }
}

__global__ __launch_bounds__(64) void mh_mfma(
    const float* __restrict__ x,
    const float* __restrict__ tables,
    const unsigned short* __restrict__ wsw,
    const float* __restrict__ b1,
    const float* __restrict__ b2,
    const float* __restrict__ b3,
    float* __restrict__ out,
    ResArr res, int n)
{
    // h1/h2 staging only: [32 rows][64 cols + 8 pad] bf16 hi + lo = 9216 B
    __shared__ __align__(16) unsigned short sAH[32 * 72];
    __shared__ __align__(16) unsigned short sAL[32 * 72];

    const int L  = threadIdx.x;
    const int ln = L & 15;
    const int q  = L >> 4;
    const long base = (long)blockIdx.x * 64;

    const float2* __restrict__ x2   = reinterpret_cast<const float2*>(x);
    const float2* __restrict__ tbl2 = reinterpret_cast<const float2*>(tables);

    // per-lane resolutions for levels q*4+t (static select on q; rule #20:
    // res.r[q*4+t] would be a runtime-indexed kernarg array -> scratch)
    float rr[4];
    #pragma unroll
    for (int t = 0; t < 4; ++t) {
        const float v0 = res.r[t], v1 = res.r[t + 4];
        const float v2 = res.r[t + 8], v3 = res.r[t + 12];
        const float a = (q & 1) ? v1 : v0;
        const float b = (q & 1) ? v3 : v2;
        rr[t] = (q & 2) ? b : a;
    }

    // biases (per-lane by output column)
    float b1v[4], b2v[4];
    #pragma unroll
    for (int nt = 0; nt < 4; ++nt) { b1v[nt] = b1[nt * 16 + ln]; b2v[nt] = b2[nt * 16 + ln]; }
    const float b3v = (ln < 3) ? b3[ln] : 0.0f;

    const f32x4 zero4 = {0.0f, 0.0f, 0.0f, 0.0f};

    for (int mh = 0; mh < 2; ++mh) {          // 32-sample halves
        // ---- encode straight into layer-1 A-fragments (registers only) ----
        // lane(ln,q): levels q*4..q*4+3 (= frag elems 2t,2t+1) of sample
        // mt*16+ln. Same math per (sample,level) as R6/R12 -> bitwise equal.
        short8 a1h[2], a1l[2];
        #pragma unroll
        for (int mt = 0; mt < 2; ++mt) {
            long srow = base + mh * 32 + mt * 16 + ln;
            if (srow >= (long)n) srow = (long)n - 1;   // clamp (loads only)
            const float2 xv = x2[srow];
            unsigned int hw[4], lw[4];
            #pragma unroll
            for (int t = 0; t < 4; ++t) {
                const float r  = rr[t];
                const float sx = xv.x * r;
                const float sy = xv.y * r;
                const float gx = floorf(sx);
                const float gy = floorf(sy);
                const unsigned ux = (unsigned)(int)gx;
                const unsigned uy = (unsigned)(int)gy;
                const unsigned hy0 = uy * PRIME1;
                const unsigned hy1 = hy0 + PRIME1;
                const unsigned i00 = ( ux       ^ hy0) & TBL_MASK;
                const unsigned i10 = ((ux + 1u) ^ hy0) & TBL_MASK;
                const unsigned i01 = ( ux       ^ hy1) & TBL_MASK;
                const unsigned i11 = ((ux + 1u) ^ hy1) & TBL_MASK;
                const float2* tl = tbl2 + (((q << 2) + t) << 14);
                const float2 t00 = tl[i00];
                const float2 t10 = tl[i10];
                const float2 t01 = tl[i01];
                const float2 t11 = tl[i11];
                const float wx0 = 1.0f - fabsf(sx - gx);
                const float wx1 = 1.0f - fabsf(sx - (gx + 1.0f));
                const float wy0 = 1.0f - fabsf(sy - gy);
                const float wy1 = 1.0f - fabsf(sy - (gy + 1.0f));
                const float w00 = wx0 * wy0;
                const float w10 = wx1 * wy0;
                const float w01 = wx0 * wy1;
                const float w11 = wx1 * wy1;
                const float f0 = fmaf(w00, t00.x, fmaf(w10, t10.x, fmaf(w01, t01.x, w11 * t11.x)));
                const float f1 = fmaf(w00, t00.y, fmaf(w10, t10.y, fmaf(w01, t01.y, w11 * t11.y)));
                const unsigned short h0 = bf16rn(f0);
                const unsigned short h1e = bf16rn(f1);
                const unsigned short l0 = bf16rn(f0 - bf16tof(h0));
                const unsigned short l1 = bf16rn(f1 - bf16tof(h1e));
                hw[t] = (unsigned)h0 | ((unsigned)h1e << 16);
                lw[t] = (unsigned)l0 | ((unsigned)l1 << 16);
            }
            const uint4v vh = { hw[0], hw[1], hw[2], hw[3] };
            const uint4v vl = { lw[0], lw[1], lw[2], lw[3] };
            a1h[mt] = __builtin_bit_cast(short8, vh);
            a1l[mt] = __builtin_bit_cast(short8, vl);
        }

        // ---------------- layer 1 ----------------
        f32x4 acc1[2][4];
        #pragma unroll
        for (int mt = 0; mt < 2; ++mt)
            #pragma unroll
            for (int nt = 0; nt < 4; ++nt) acc1[mt][nt] = zero4;

        #pragma unroll
        for (int nt = 0; nt < 4; ++nt) {
            const short8 bh = ld8(&wsw[W1H_OFF + (nt * 16 + ln) * 32 + q * 8]);
            const short8 bl = ld8(&wsw[W1L_OFF + (nt * 16 + ln) * 32 + q * 8]);
            #pragma unroll
            for (int mt = 0; mt < 2; ++mt) {
                f32x4 a = acc1[mt][nt];
                a = MFMA(a1l[mt], bh, a);
                a = MFMA(a1h[mt], bl, a);
                a = MFMA(a1h[mt], bh, a);
                acc1[mt][nt] = a;
            }
        }
        // epilogue: bias + relu + split -> sAH/sAL rows 0..31 (fresh per
        // half; same-wave DS ops retire in order, single-wave block)
        #pragma unroll
        for (int mt = 0; mt < 2; ++mt)
            #pragma unroll
            for (int nt = 0; nt < 4; ++nt) {
                const int col = nt * 16 + ln;
                #pragma unroll
                for (int r = 0; r < 4; ++r) {
                    float v = fmaxf(acc1[mt][nt][r] + b1v[nt], 0.0f);
                    const unsigned short hb = bf16rn(v);
                    const unsigned short lb = bf16rn(v - bf16tof(hb));
                    const int rl = mt * 16 + q * 4 + r;
                    sAH[rl * 72 + col] = hb;
                    sAL[rl * 72 + col] = lb;
                }
            }

        // ---------------- layer 2 ----------------
        short8 a2h[2][2], a2l[2][2];
        #pragma unroll
        for (int mt = 0; mt < 2; ++mt)
            #pragma unroll
            for (int ks = 0; ks < 2; ++ks) {
                const int row = mt * 16 + ln;
                a2h[mt][ks] = ld8(&sAH[row * 72 + ks * 32 + q * 8]);
                a2l[mt][ks] = ld8(&sAL[row * 72 + ks * 32 + q * 8]);
            }
        f32x4 acc2[2][4];
        #pragma unroll
        for (int mt = 0; mt < 2; ++mt)
            #pragma unroll
            for (int nt = 0; nt < 4; ++nt) acc2[mt][nt] = zero4;

        #pragma unroll
        for (int nt = 0; nt < 4; ++nt)
            #pragma unroll
            for (int ks = 0; ks < 2; ++ks) {
                const short8 bh = ld8(&wsw[W2H_OFF + (nt * 16 + ln) * 64 + ks * 32 + q * 8]);
                const short8 bl = ld8(&wsw[W2L_OFF + (nt * 16 + ln) * 64 + ks * 32 + q * 8]);
                #pragma unroll
                for (int mt = 0; mt < 2; ++mt) {
                    f32x4 a = acc2[mt][nt];
                    a = MFMA(a2l[mt][ks], bh, a);
                    a = MFMA(a2h[mt][ks], bl, a);
                    a = MFMA(a2h[mt][ks], bh, a);
                    acc2[mt][nt] = a;
                }
            }
        // epilogue -> overwrite sAH/sAL (A-frags above already read)
        #pragma unroll
        for (int mt = 0; mt < 2; ++mt)
            #pragma unroll
            for (int nt = 0; nt < 4; ++nt) {
                const int col = nt * 16 + ln;
                #pragma unroll
                for (int r = 0; r < 4; ++r) {
                    float v = fmaxf(acc2[mt][nt][r] + b2v[nt], 0.0f);
                    const unsigned short hb = bf16rn(v);
                    const unsigned short lb = bf16rn(v - bf16tof(hb));
                    const int rl = mt * 16 + q * 4 + r;
                    sAH[rl * 72 + col] = hb;
                    sAL[rl * 72 + col] = lb;
                }
            }

        // ---------------- layer 3 ----------------
        short8 a3h[2][2], a3l[2][2];
        #pragma unroll
        for (int mt = 0; mt < 2; ++mt)
            #pragma unroll
            for (int ks = 0; ks < 2; ++ks) {
                const int row = mt * 16 + ln;
                a3h[mt][ks] = ld8(&sAH[row * 72 + ks * 32 + q * 8]);
                a3l[mt][ks] = ld8(&sAL[row * 72 + ks * 32 + q * 8]);
            }
        f32x4 acc3[2] = {zero4, zero4};
        #pragma unroll
        for (int ks = 0; ks < 2; ++ks) {
            // W3 pre-padded to 16 rows (3..15 zero) -> no divergent mask
            const short8 bh = ld8(&wsw[W3H_OFF + ln * 64 + ks * 32 + q * 8]);
            const short8 bl = ld8(&wsw[W3L_OFF + ln * 64 + ks * 32 + q * 8]);
            #pragma unroll
            for (int mt = 0; mt < 2; ++mt) {
                f32x4 a = acc3[mt];
                a = MFMA(a3l[mt][ks], bh, a);
                a = MFMA(a3h[mt][ks], bl, a);
                a = MFMA(a3h[mt][ks], bh, a);
                acc3[mt] = a;
            }
        }
        // store: C col = ln (channel, <3), rows = samples
        if (ln < 3) {
            #pragma unroll
            for (int mt = 0; mt < 2; ++mt)
                #pragma unroll
                for (int r = 0; r < 4; ++r) {
                    const long sg = base + mh * 32 + mt * 16 + q * 4 + r;
                    if (sg < (long)n) out[sg * 3 + ln] = acc3[mt][r] + b3v;
                }
        }
    }
}

extern "C" void kernel_launch(void* const* d_in, const int* in_sizes, int n_in,
                              void* d_out, int out_size, void* d_ws, size_t ws_size,
                              hipStream_t stream) {
    const float* x      = (const float*)d_in[0];
    const float* tables = (const float*)d_in[1];
    const float* W1     = (const float*)d_in[2];
    const float* b1v    = (const float*)d_in[3];
    const float* W2     = (const float*)d_in[4];
    const float* b2v    = (const float*)d_in[5];
    const float* W3     = (const float*)d_in[6];
    const float* b3v    = (const float*)d_in[7];
    float* out = (float*)d_out;
    unsigned short* wsu = (unsigned short*)d_ws;

    const int n = in_sizes[0] / 2;   // B

    // Replicate numpy's RES computation on the host (glibc libm, float64).
    ResArr ra;
    const double bb = exp((log(512.0) - log(16.0)) / 15.0);
    for (int k = 0; k < 16; ++k) ra.r[k] = (float)floor(16.0 * pow(bb, (double)k));

    // Prepass: hi/lo bf16 weight split into workspace (stream-ordered).
    hipLaunchKernelGGL(split_weights, dim3(8), dim3(256), 0, stream, W1, W2, W3, wsu);

    dim3 grid((n + 63) / 64), block(64);
    hipLaunchKernelGGL(mh_mfma, grid, block, 0, stream,
                       x, tables, wsu, b1v, b2v, b3v, out, ra, n);
}